// Round 13
// baseline (280.966 us; speedup 1.0000x reference)
//
#include <hip/hip_runtime.h>
#include <hip/hip_bf16.h>
#include <cstdint>

#define NANCH 17064
#define KTOP  1000
#define NCLS  80

typedef unsigned long long u64;
typedef unsigned int u32;

__device__ __forceinline__ float sigmoidf_(float x) {
  return 1.0f / (1.0f + expf(-x));
}

// v_readlane-based 64-bit broadcast: no DS pipe, no lgkmcnt, pre-issuable.
__device__ __forceinline__ u64 readlane_u64(u64 v, int l) {
  u32 lo = (u32)__builtin_amdgcn_readlane((int)(u32)v, l);
  u32 hi = (u32)__builtin_amdgcn_readlane((int)(u32)(v >> 32), l);
  return ((u64)hi << 32) | lo;
}

__device__ __forceinline__ u64 shfl_xor_u64(u64 v, int mask) {
  u32 lo = (u32)__shfl_xor((int)(u32)v, mask, 64);
  u32 hi = (u32)__shfl_xor((int)(u32)(v >> 32), mask, 64);
  return ((u64)hi << 32) | lo;
}

// ---------------------------------------------------------------------------
// K1: per-anchor score / class / box decode.  QUAD-ANCHOR FLOAT4 FORM.
// Each thread owns 4 consecutive anchors.  Valid because every level
// boundary, hw, and row width is a multiple of 4: a quad never straddles a
// level or a row, and every float4 address is 16B-aligned.  Per-anchor FP
// sequence identical to the scalar version (bit-exact).
// ---------------------------------------------------------------------------
__global__ void __launch_bounds__(256) fcos_score_kernel(
    const float* __restrict__ cls0, const float* __restrict__ cnt0, const float* __restrict__ reg0,
    const float* __restrict__ cls1, const float* __restrict__ cnt1, const float* __restrict__ reg1,
    const float* __restrict__ cls2, const float* __restrict__ cnt2, const float* __restrict__ reg2,
    const float* __restrict__ cls3, const float* __restrict__ cnt3, const float* __restrict__ reg3,
    const float* __restrict__ cls4, const float* __restrict__ cnt4, const float* __restrict__ reg4,
    u64* __restrict__ keys, int* __restrict__ classes, float4* __restrict__ boxes)
{
  int t = blockIdx.x * blockDim.x + threadIdx.x;   // quad index
  int b = blockIdx.y;
  if (t >= NANCH / 4) return;                      // 4266 quads
  int a0 = t * 4;

  const float *clsP, *cntP, *regP;
  int hw, wlog, stride, half, local0;
  if (a0 < 12800)      { clsP=cls0; cntP=cnt0; regP=reg0; hw=12800; wlog=7; stride=8;   half=4;  local0=a0; }
  else if (a0 < 16000) { clsP=cls1; cntP=cnt1; regP=reg1; hw=3200;  wlog=6; stride=16;  half=8;  local0=a0-12800; }
  else if (a0 < 16800) { clsP=cls2; cntP=cnt2; regP=reg2; hw=800;   wlog=5; stride=32;  half=16; local0=a0-16000; }
  else if (a0 < 17008) { clsP=cls3; cntP=cnt3; regP=reg3; hw=208;   wlog=4; stride=64;  half=32; local0=a0-16800; }
  else                 { clsP=cls4; cntP=cnt4; regP=reg4; hw=56;    wlog=3; stride=128; half=64; local0=a0-17008; }

  int y  = local0 >> wlog;                  // same row for all 4 anchors
  int x0 = local0 & ((1 << wlog) - 1);      // x0 % 4 == 0, x0+3 <= w-1

  // max/argmax over sigmoid values, 4 anchors in parallel (same c order,
  // strict '>' per anchor == jnp.argmax first-max tie-break)
  const float* cp = clsP + (long)b * NCLS * hw + local0;
  float best[4] = {-1.0f, -1.0f, -1.0f, -1.0f};
  int   bestc[4] = {0, 0, 0, 0};
  #pragma unroll 4
  for (int c = 0; c < NCLS; ++c) {
    float4 v = *reinterpret_cast<const float4*>(cp + (long)c * hw);
    float s0 = sigmoidf_(v.x), s1 = sigmoidf_(v.y), s2 = sigmoidf_(v.z), s3 = sigmoidf_(v.w);
    if (s0 > best[0]) { best[0] = s0; bestc[0] = c; }
    if (s1 > best[1]) { best[1] = s1; bestc[1] = c; }
    if (s2 > best[2]) { best[2] = s2; bestc[2] = c; }
    if (s3 > best[3]) { best[3] = s3; bestc[3] = c; }
  }

  float4 cv = *reinterpret_cast<const float4*>(cntP + (long)b * hw + local0);
  float csv[4] = { sigmoidf_(cv.x), sigmoidf_(cv.y), sigmoidf_(cv.z), sigmoidf_(cv.w) };

  const float* rp = regP + (long)b * 4 * hw + local0;
  float4 rA = *reinterpret_cast<const float4*>(rp);            // l
  float4 rB = *reinterpret_cast<const float4*>(rp + hw);       // t
  float4 rC = *reinterpret_cast<const float4*>(rp + 2 * hw);   // r
  float4 rD = *reinterpret_cast<const float4*>(rp + 3 * hw);   // b
  float l_[4] = { rA.x, rA.y, rA.z, rA.w };
  float t_[4] = { rB.x, rB.y, rB.z, rB.w };
  float r_[4] = { rC.x, rC.y, rC.z, rC.w };
  float d_[4] = { rD.x, rD.y, rD.z, rD.w };

  long gi0 = (long)b * NANCH + a0;
  float cy = (float)(y * stride + half);
  int4 cls4o;
  #pragma unroll
  for (int i = 0; i < 4; ++i) {
    float score = __fsqrt_rn(__fmul_rn(best[i], csv[i]));
    float cx = (float)((x0 + i) * stride + half);
    keys[gi0 + i] = ((u64)__float_as_uint(score) << 32) | (u32)(~(u32)(a0 + i));
    boxes[gi0 + i] = make_float4(cx - l_[i], cy - t_[i], cx + r_[i], cy + d_[i]);
    ((int*)&cls4o)[i] = bestc[i] + 1;
  }
  *reinterpret_cast<int4*>(classes + gi0) = cls4o;   // gi0 % 4 == 0 -> aligned
}

// ---------------------------------------------------------------------------
// K2: per-batch top-1000.
//  - keys register-cached (17/thread): histogram + compaction passes read
//    VGPRs, not L2.
//  - passes d=24,d=16 skipped: key bits 16..31 are 0xFFFF for every key
//    (a < 2^15), so those passes provably pick bin 255 with krem unchanged;
//    prefix gets 0xFFFF appended after the d=32 pass.  Bit-exact.
//  - hybrid bitonic: stride>=64 stages in LDS (10 steps, 2 barriers each),
//    stride<=32 stages via shfl_xor in registers (45 steps, 0 barriers).
// ---------------------------------------------------------------------------
struct ShmA {
  u64 skeys[1024];      // 8 KB
  u32 hist[256];        // 1 KB
  u32 whist[16][256];   // 16 KB
};

__global__ void __launch_bounds__(1024) fcos_topk_kernel(
    const u64* __restrict__ keys, const int* __restrict__ classes,
    const float4* __restrict__ boxes,
    float* __restrict__ t_score, int* __restrict__ t_cls, float4* __restrict__ t_box,
    float* __restrict__ ox1, float* __restrict__ oy1,
    float* __restrict__ ox2, float* __restrict__ oy2,
    float* __restrict__ oarea, u64* __restrict__ validbits)
{
  __shared__ ShmA sh;
  __shared__ u64 s_prefix;
  __shared__ u32 s_krem, s_cnt;
  __shared__ float s_red[16];
  __shared__ float s_maxc;

  const int tid = threadIdx.x;
  const int b   = blockIdx.x;
  const int lane = tid & 63;
  const u64* bkeys = keys + (long)b * NANCH;

  // register-cache this thread's keys (p*1024+tid, p=0..16)
  u64 rk[17];
  #pragma unroll
  for (int p = 0; p < 17; ++p) {
    int i = p * 1024 + tid;
    rk[p] = (i < NANCH) ? bkeys[i] : 0;   // pad value never used (guarded below)
  }

  if (tid == 0) { s_prefix = 0; s_krem = KTOP; s_cnt = 0; }
  __syncthreads();

  // ---- A: radix select; informative passes only ---------------------------
  const int dlist[6] = {56, 48, 40, 32, 8, 0};
  #pragma unroll
  for (int pi = 0; pi < 6; ++pi) {
    const int d = dlist[pi];
    for (int i = tid; i < 16 * 256; i += 1024) ((u32*)sh.whist)[i] = 0;
    __syncthreads();
    u64 pfx = s_prefix;
    u32* myh = sh.whist[tid >> 6];
    #pragma unroll
    for (int p = 0; p < 17; ++p) {
      if (p * 1024 + tid < NANCH) {
        u64 k = rk[p];
        bool ok = (pi == 0) || ((k >> (d + 8)) == pfx);  // short-circuit: no shift-by-64
        if (ok) atomicAdd(&myh[(u32)((k >> d) & 255)], 1u);
      }
    }
    __syncthreads();
    if (tid < 256) {
      u32 s = 0;
      #pragma unroll
      for (int w = 0; w < 16; ++w) s += sh.whist[w][tid];
      sh.hist[tid] = s;
    }
    __syncthreads();
    if (tid < 64) {
      u32 h0 = sh.hist[lane * 4 + 0], h1 = sh.hist[lane * 4 + 1];
      u32 h2 = sh.hist[lane * 4 + 2], h3 = sh.hist[lane * 4 + 3];
      u32 lsum = h0 + h1 + h2 + h3;
      u32 incl = lsum;
      #pragma unroll
      for (int off = 1; off < 64; off <<= 1) {
        u32 nv = __shfl_down(incl, off, 64);
        if (lane + off < 64) incl += nv;
      }
      u32 kr = s_krem;
      u64 ball = __ballot(incl >= kr);
      int selLane = 63 - __clzll(ball);
      if (lane == selLane) {
        u32 A = incl - lsum;
        u32 cum3 = A;
        u32 cum2 = A + h3;
        u32 cum1 = cum2 + h2;
        u32 cum0 = cum1 + h1;
        int bin; u32 cum;
        if (cum3 + h3 >= kr)      { bin = lane * 4 + 3; cum = cum3; }
        else if (cum2 + h2 >= kr) { bin = lane * 4 + 2; cum = cum2; }
        else if (cum1 + h1 >= kr) { bin = lane * 4 + 1; cum = cum1; }
        else                      { bin = lane * 4 + 0; cum = cum0; }
        u64 np = (s_prefix << 8) | (u32)bin;
        if (pi == 3) np = (np << 16) | 0xFFFFull;  // inject constant bytes 3,2
        s_prefix = np;
        s_krem   = kr - cum;
      }
    }
    __syncthreads();
  }
  const u64 T = s_prefix;   // exact 1000th-largest key (keys are unique)

  // ---- B: compact (from registers) + hybrid bitonic sort ------------------
  sh.skeys[tid] = ~0ULL;    // pad sorts to the end (ascending on inverted keys)
  __syncthreads();
  #pragma unroll
  for (int p = 0; p < 17; ++p) {
    if (p * 1024 + tid < NANCH) {
      u64 k = rk[p];
      if (k >= T) { u32 pos = atomicAdd(&s_cnt, 1u); if (pos < 1024) sh.skeys[pos] = ~k; }
    }
  }
  __syncthreads();

  u64 val = sh.skeys[tid];
  for (u32 sz = 2; sz <= 1024; sz <<= 1) {
    for (u32 st = sz >> 1; st > 0; st >>= 1) {
      bool up    = ((tid & sz) == 0);
      bool lower = ((tid & st) == 0);
      bool keepMin = (lower == up);
      u64 part;
      if (st >= 64) {
        __syncthreads();               // prior reads done before overwrite
        sh.skeys[tid] = val;
        __syncthreads();
        part = sh.skeys[tid ^ st];
      } else {
        part = shfl_xor_u64(val, (int)st);   // wave-synchronous, no barrier
      }
      bool less = (val < part);
      val = (keepMin == less) ? val : part;  // keepMin ? min : max
    }
  }
  // thread tid now holds the rank-tid (ascending inverted) element in a register

  // ---- C: extract rank tid, gather, max_coord, offset boxes ---------------
  u64 key = ~val;
  float score = __uint_as_float((u32)(key >> 32));
  int   idx   = (int)(~(u32)(key & 0xFFFFFFFFu));
  float4 box  = make_float4(0.f, 0.f, 0.f, 0.f);
  int    cls  = 0;
  if (tid < KTOP) {
    long gi = (long)b * NANCH + idx;
    cls = classes[gi];
    box = boxes[gi];
  } else {
    score = 0.0f;
  }
  int valid = (tid < KTOP) && (score >= 0.05f);

  float m = valid ? fmaxf(fmaxf(box.x, box.y), fmaxf(box.z, box.w)) : 0.0f;
  #pragma unroll
  for (int o = 32; o > 0; o >>= 1) m = fmaxf(m, __shfl_xor(m, o, 64));
  if (lane == 0) s_red[tid >> 6] = m;
  __syncthreads();
  if (tid == 0) {
    float mm = 0.0f;
    #pragma unroll
    for (int i2 = 0; i2 < 16; ++i2) mm = fmaxf(mm, s_red[i2]);
    s_maxc = mm;
  }
  __syncthreads();

  float off = __fmul_rn((float)cls, __fadd_rn(s_maxc, 1.0f));
  float X1 = box.x + off, Y1 = box.y + off, X2 = box.z + off, Y2 = box.w + off;

  int gi = b * 1024 + tid;
  t_score[gi] = score;
  t_cls[gi]   = cls;
  t_box[gi]   = box;
  ox1[gi] = X1; oy1[gi] = Y1; ox2[gi] = X2; oy2[gi] = Y2;
  oarea[gi] = __fmul_rn(__fadd_rn(__fsub_rn(X2, X1), 1.0f),
                        __fadd_rn(__fsub_rn(Y2, Y1), 1.0f));
  u64 vb = __ballot(valid != 0);
  if (lane == 0) validbits[b * 16 + (tid >> 6)] = vb;
}

// ---------------------------------------------------------------------------
// K3: suppression matrix build.  (UNCHANGED)
// ---------------------------------------------------------------------------
__global__ void __launch_bounds__(256) fcos_iou_kernel(
    const float* __restrict__ ox1, const float* __restrict__ oy1,
    const float* __restrict__ ox2, const float* __restrict__ oy2,
    const float* __restrict__ oarea, u64* __restrict__ mat)
{
  __shared__ float sx1[1024], sy1[1024], sx2[1024], sy2[1024], sa[1024];
  const int tid = threadIdx.x;
  const int b   = blockIdx.y;
  const int lane = tid & 63;

  for (int k = tid; k < 1024; k += 256) {
    int gi = b * 1024 + k;
    sx1[k] = ox1[gi]; sy1[k] = oy1[gi];
    sx2[k] = ox2[gi]; sy2[k] = oy2[gi];
    sa[k]  = oarea[gi];
  }
  __syncthreads();

  int w = blockIdx.x * 256 + tid;
  if (w >= KTOP * 16) return;
  int r  = w >> 4;
  int wc = w & 15;

  float rx1 = sx1[r], ry1 = sy1[r], rx2 = sx2[r], ry2 = sy2[r], ra = sa[r];
  u64 bits = 0;
  for (int kk = 0; kk < 64; ++kk) {
    int k2 = (kk + lane) & 63;
    int j  = wc * 64 + k2;
    if (j < KTOP) {
      float xmn = fmaxf(rx1, sx1[j]);
      float ymn = fmaxf(ry1, sy1[j]);
      float xmx = fminf(rx2, sx2[j]);
      float ymx = fminf(ry2, sy2[j]);
      float dx    = fmaxf(__fsub_rn(xmx, xmn), 0.0f);
      float dy    = fmaxf(__fsub_rn(ymx, ymn), 0.0f);
      float inter = __fmul_rn(dx, dy);
      float den   = __fsub_rn(__fadd_rn(ra, sa[j]), inter);
      float iou   = __fdiv_rn(inter, den);
      if (iou > 0.6f) bits |= (1ULL << k2);
    }
  }
  mat[((long)b * KTOP + r) * 16 + wc] = bits;
}

// ---------------------------------------------------------------------------
// K4: greedy scan, group-diagonal + readlane form.  (UNCHANGED)
// ---------------------------------------------------------------------------
__global__ void __launch_bounds__(256) fcos_scan_kernel(
    const u64* __restrict__ mat, const u64* __restrict__ validbits,
    const float* __restrict__ t_score, const int* __restrict__ t_cls,
    const float4* __restrict__ t_box, float* __restrict__ out)
{
  __shared__ u64 s_keep[16];
  const int tid = threadIdx.x;
  const int b   = blockIdx.x;

  if (tid < 64) {
    const int lane = tid;
    const int q = lane >> 4, r = lane & 15;
    const u64* mb = mat + (long)b * KTOP * 16;
    u64 alive = (lane < 16) ? validbits[b * 16 + lane] : 0;

    u64 dw = mb[(long)lane * 16 + 0];

    for (int g = 0; g < 16; ++g) {
      u64 dwn = 0;
      if (g < 15) {
        int rn = (g + 1) * 64 + lane; if (rn > KTOP - 1) rn = KTOP - 1;
        dwn = mb[(long)rn * 16 + (g + 1)];
      }

      u64 aw = readlane_u64(alive, g);
      u64 s  = ~aw;
      u64 keepm = 0;
      #pragma unroll
      for (int i = 0; i < 64; ++i) {
        u64 rowm = readlane_u64(dw, i);
        u64 kb   = ((~s) >> i) & 1ull;
        keepm |= kb << i;
        s     |= rowm & (0ull - kb);
      }
      if (lane == 0) s_keep[g] = keepm;

      u64 rem = 0;
      #pragma unroll
      for (int t = 0; t < 16; ++t) {
        int i   = q * 16 + t;
        int row = g * 64 + i; if (row > KTOP - 1) row = KTOP - 1;
        u64 wv  = mb[(long)row * 16 + r];
        rem |= wv & (0ull - ((keepm >> i) & 1ull));
      }
      rem |= __shfl_xor(rem, 16, 64);
      rem |= __shfl_xor(rem, 32, 64);
      if (lane < 16) alive &= ~rem;

      dw = dwn;
    }
  }
  __syncthreads();

  for (int i = tid; i < KTOP; i += 256) {
    int kp = (int)((s_keep[i >> 6] >> (i & 63)) & 1ULL);
    float kf = kp ? 1.0f : 0.0f;
    int gi = b * KTOP + i;
    int ti = b * 1024 + i;
    float sc  = t_score[ti];
    int   cls = t_cls[ti];
    float4 bx = t_box[ti];
    out[gi]         = sc * kf;
    out[16000 + gi] = kp ? (float)cls : 0.0f;
    float4 ob = make_float4(bx.x * kf, bx.y * kf, bx.z * kf, bx.w * kf);
    *reinterpret_cast<float4*>(out + 32000 + (long)gi * 4) = ob;
    out[96000 + gi] = kf;
  }
}

// ---------------------------------------------------------------------------
extern "C" void kernel_launch(void* const* d_in, const int* in_sizes, int n_in,
                              void* d_out, int out_size, void* d_ws, size_t ws_size,
                              hipStream_t stream) {
  const float *cls[5], *cnt[5], *reg[5];
  for (int i = 0; i < 5; ++i) {
    cls[i] = (const float*)d_in[3*i + 0];
    cnt[i] = (const float*)d_in[3*i + 1];
    reg[i] = (const float*)d_in[3*i + 2];
  }
  char* ws = (char*)d_ws;
  u64*    keys    = (u64*)ws;                    // 16*17064*8 = 2,184,192 B
  u64*    mat     = (u64*)ws;                    // 2,048,000 B (aliases keys; K3 runs after K2)
  int*    classes = (int*)(ws + 2184192);        // 1,092,096 B
  float4* boxes   = (float4*)(ws + 3276288);     // 4,368,384 B
  float*  t_score = (float*)(ws + 7644672);
  int*    t_cls   = (int*)  (ws + 7710208);
  float4* t_box   = (float4*)(ws + 7775744);
  float*  ox1     = (float*)(ws + 8037888);
  float*  oy1     = (float*)(ws + 8103424);
  float*  ox2     = (float*)(ws + 8168960);
  float*  oy2     = (float*)(ws + 8234496);
  float*  oarea   = (float*)(ws + 8300032);
  u64*    vbits   = (u64*)  (ws + 8365568);
  float*  out     = (float*)d_out;

  dim3 g1((NANCH / 4 + 255) / 256, 16);          // 4266 quads -> 17 x 16 blocks
  fcos_score_kernel<<<g1, 256, 0, stream>>>(
      cls[0], cnt[0], reg[0], cls[1], cnt[1], reg[1], cls[2], cnt[2], reg[2],
      cls[3], cnt[3], reg[3], cls[4], cnt[4], reg[4], keys, classes, boxes);

  fcos_topk_kernel<<<16, 1024, 0, stream>>>(
      keys, classes, boxes, t_score, t_cls, t_box, ox1, oy1, ox2, oy2, oarea, vbits);

  fcos_iou_kernel<<<dim3(63, 16), 256, 0, stream>>>(ox1, oy1, ox2, oy2, oarea, mat);

  fcos_scan_kernel<<<16, 256, 0, stream>>>(mat, vbits, t_score, t_cls, t_box, out);
}